// Round 10
// baseline (150.012 us; speedup 1.0000x reference)
//
#include <hip/hip_runtime.h>

// ISTA T=5, LAM=0.1, B=L=4096, K=128.
// R13: single-launch, self-contained blocks, 3 blocks/CU co-residency.
//  u = corr(y - corr(y,h), rev(h)) == (interior) one 255-tap correlation
//    G[t] = [t in [-63,64]] h[64-t] - ac[|t-1|],  ac[tau]=sum_m h[m]h[m+tau].
//  512 stream blocks (512 thr, 16 rows x 2048 cols) + 256 edge blocks
//  (512 thr, one 16-row strip, BOTH 64-col edge strips). ~52 KB LDS ->
//  3 blocks/CU = 24 resident waves/CU.
//  Stream: counted-vmcnt 6-slot ring of 128-col fp32 segs (pitch 775 dw:
//  bank shift 7 = odd -> full 32-bank spread, free 2-way). Per phase k:
//  issue seg k+4 (4 size-4 DMA/wave); slide B by 4 windows + read 4 new;
//  9 MFMA; store; s_waitcnt vmcnt(4) [retires seg k+3 + store, keeps k+4
//  in flight ACROSS the barrier]; s_barrier; sched_barrier(0).
//  Tables (G/autocorr) built in-block, overlapped with the DMA prologue:
//  h-load issued BEFORE prologue -> vmcnt(20) retires it w/o draining DMAs;
//  raw s_barrier + lgkmcnt(0) (no vmcnt drain) between table stages.
//  Seg m read by phases m-2..m; its slot overwritten by seg m+6 issued at
//  phase m+2 AFTER phase m+1's barrier -> one-phase safety margin.
//  OOB halo segs DMA from a 256-B zero block in d_ws (memset on stream).
//  ISTA closed form (constant u): x_5 = 5*soft(s*u, LAM).

typedef __bf16 bf16;
typedef __bf16 bf16x4 __attribute__((ext_vector_type(4)));
typedef __bf16 bf16x8 __attribute__((ext_vector_type(8)));
typedef float f32x4 __attribute__((ext_vector_type(4)));

#define LAM 0.1f
#define RPDW 775                  // ring row pitch, fp32 dwords (3100 B)
#define RINGB (16 * RPDW * 4)     // 49600 B
#define SMEMB (RINGB + 1024 + 1024 + 768)   // +hs[256]f +acp[256]f +gpad[384]
// edge-path LDS partition (overlays ring region):
#define PYE 360                   // y strip pitch bf16 (352 needed)
#define PRE 216                   // r strip pitch bf16 (208 needed)

// fp32 LDS ring row -> bf16x8 fragment (X = ring dword offset, mult of 8)
__device__ __forceinline__ bf16x8 ldfragX(const float* __restrict__ rowb,
                                          int X) {
  float4 v0 = *reinterpret_cast<const float4*>(rowb + X);
  float4 v1 = *reinterpret_cast<const float4*>(rowb + X + 4);
  bf16x8 b;
  b[0] = (bf16)v0.x; b[1] = (bf16)v0.y; b[2] = (bf16)v0.z; b[3] = (bf16)v0.w;
  b[4] = (bf16)v1.x; b[5] = (bf16)v1.y; b[6] = (bf16)v1.z; b[7] = (bf16)v1.w;
  return b;
}

__global__ __launch_bounds__(512) void ista_all(
    const float* __restrict__ y, const float* __restrict__ h,
    const float* __restrict__ zsrc, const float* __restrict__ step,
    float* __restrict__ out) {
  __shared__ __align__(16) char smem[SMEMB];
  const int tid = threadIdx.x;
  const int lane = tid & 63;
  const int li = lane & 15;
  const int quad = lane >> 4;
  const int wave = tid >> 6;            // 0..7
  const int bid = blockIdx.x;
  const float s = step[0];

  if (bid < 512) {
    // ============ stream: 16 rows x 2048 cols, 16 phases of 128 ===========
    const int b0 = (bid & 255) * 16;    // rowgroup-major -> XCD pairing
    const int cb = (bid >> 8) * 2048;
    float* ringf = reinterpret_cast<float*>(smem);
    float* hs = reinterpret_cast<float*>(smem + RINGB);
    float* acp = hs + 256;
    bf16* gpad = reinterpret_cast<bf16*>(acp + 256);

    // -- 1. h load FIRST (vmem in waves 0,1 only), pinned before prologue --
    float hreg = 0.f;
    if (tid < 128) hreg = h[tid];
    asm volatile("" ::: "memory");      // keep h-load ahead of DMA issue

    // -- 2. DMA prologue: segs -1..3 (4 issues/wave/seg) --
    auto issue_seg = [&](int m) {
      const int base = cb + 128 * m;
      const bool oob = ((unsigned)base >= 4096u);
      const int slotB = (((m + 12) % 6) * 128) << 2;
#pragma unroll
      for (int t = 0; t < 4; ++t) {
        const int rr = wave * 2 + (t >> 1);
        const int q = t & 1;
        const float* src =
            oob ? (zsrc + lane)
                : (y + (size_t)(b0 + rr) * 4096 + base + 64 * q + lane);
        char* dst = smem + rr * (RPDW * 4) + slotB + q * 256;
        __builtin_amdgcn_global_load_lds(
            (const __attribute__((address_space(1))) void*)src,
            (__attribute__((address_space(3))) void*)dst, 4, 0, 0);
      }
    };
#pragma unroll
    for (int m = -1; m <= 3; ++m) issue_seg(m);

    // -- 3. table build, overlapped with DMA (raw barriers: no vmcnt drain)
    asm volatile("s_waitcnt vmcnt(20)" ::: "memory");   // retires h-load only
    if (tid < 256) hs[tid] = (tid < 128) ? hreg : 0.f;
    asm volatile("s_waitcnt lgkmcnt(0)" ::: "memory");
    __builtin_amdgcn_s_barrier();

    if (tid < 256) {                    // autocorr partials (waves 0-3)
      const int tau = tid & 127;
      const int m0 = (tid >> 7) * 64;
      float p0 = 0.f, p1 = 0.f, p2 = 0.f, p3 = 0.f;
      for (int m = m0; m < m0 + 64; m += 4) {
        p0 += hs[m] * hs[m + tau];         p1 += hs[m + 1] * hs[m + 1 + tau];
        p2 += hs[m + 2] * hs[m + 2 + tau]; p3 += hs[m + 3] * hs[m + 3 + tau];
      }
      acp[tid] = (p0 + p1) + (p2 + p3);
    }
    asm volatile("s_waitcnt lgkmcnt(0)" ::: "memory");
    __builtin_amdgcn_s_barrier();

    if (tid < 128) {                    // G[t] at p=t+144
      const int tau = tid;
      float ac = acp[tid] + acp[tid + 128];
      float g1 = (tau <= 63) ? hs[63 - tau] : 0.f;
      gpad[145 + tau] = (bf16)(g1 - ac);
      if (tau > 0) {
        float g2 = (tau <= 64) ? hs[63 + tau] : 0.f;
        gpad[145 - tau] = (bf16)(g2 - ac);
      }
    } else if (tid < 256) {             // zero-pad gpad edges
      const int r = tid - 128;
      if (r < 18) gpad[r] = (bf16)0.f;
      if (273 + r < 384) gpad[273 + r] = (bf16)0.f;
    }
    asm volatile("s_waitcnt lgkmcnt(0)" ::: "memory");
    __builtin_amdgcn_s_barrier();

    // -- 4. AG fragments: A[m=li][k=quad*8+j] = G[144+qo-li+(dd-4)*32+j] --
    bf16x8 AG[9];
    {
      const int off = 144 + quad * 8 - li;
#pragma unroll
      for (int dd = 0; dd < 9; ++dd) {
        const int o = off + (dd - 4) * 32;   // in [1,296]
        bf16x8 a;
#pragma unroll
        for (int j = 0; j < 8; ++j) a[j] = gpad[o + j];
        AG[dd] = a;
      }
    }

    // -- 5. gate phase 0: segs -1..2 landed (16 of 20 retired), seg 3 flies
    asm volatile("s_waitcnt vmcnt(4)" ::: "memory");
    __builtin_amdgcn_s_barrier();
    __builtin_amdgcn_sched_barrier(0);

    const int qo = quad << 3;
    const float* rowb = ringf + li * RPDW;
    float* orow = out + (size_t)(b0 + li) * 4096 + cb + (quad << 2);

    bf16x8 B[9];                        // initial 9 windows, tile tc0=16*wave
#pragma unroll
    for (int dd = 0; dd < 9; ++dd) {
      int col = 16 * wave + (dd - 4) * 32 + qo;
      B[dd] = ldfragX(rowb, ((col % 768) + 768) % 768);
    }

    for (int k = 0; k < 16; ++k) {
      issue_seg(k + 4);                 // slot (k+4)%6; lands by end of k+1
      const int tc = 128 * k + 16 * wave;
      if (k > 0) {                      // slide 128 cols: keep 5, read 4 new
#pragma unroll
        for (int i = 0; i < 5; ++i) B[i] = B[i + 4];
#pragma unroll
        for (int dd = 5; dd < 9; ++dd) {
          int col = tc + (dd - 4) * 32 + qo;   // segs k..k+2 (landed)
          B[dd] = ldfragX(rowb, col % 768);
        }
      }
      f32x4 acc0 = {0.f, 0.f, 0.f, 0.f};
      f32x4 acc1 = {0.f, 0.f, 0.f, 0.f};
      acc0 = __builtin_amdgcn_mfma_f32_16x16x32_bf16(AG[0], B[0], acc0, 0, 0, 0);
      acc1 = __builtin_amdgcn_mfma_f32_16x16x32_bf16(AG[1], B[1], acc1, 0, 0, 0);
      acc0 = __builtin_amdgcn_mfma_f32_16x16x32_bf16(AG[2], B[2], acc0, 0, 0, 0);
      acc1 = __builtin_amdgcn_mfma_f32_16x16x32_bf16(AG[3], B[3], acc1, 0, 0, 0);
      acc0 = __builtin_amdgcn_mfma_f32_16x16x32_bf16(AG[4], B[4], acc0, 0, 0, 0);
      acc1 = __builtin_amdgcn_mfma_f32_16x16x32_bf16(AG[5], B[5], acc1, 0, 0, 0);
      acc0 = __builtin_amdgcn_mfma_f32_16x16x32_bf16(AG[6], B[6], acc0, 0, 0, 0);
      acc1 = __builtin_amdgcn_mfma_f32_16x16x32_bf16(AG[7], B[7], acc1, 0, 0, 0);
      acc0 = __builtin_amdgcn_mfma_f32_16x16x32_bf16(AG[8], B[8], acc0, 0, 0, 0);
      const int tabs = cb + tc;
      if (tabs >= 64 && tabs < 4032) {  // edge strips owned by edge blocks
        float4 xv;
#pragma unroll
        for (int e = 0; e < 4; ++e) {
          float su = s * (acc0[e] + acc1[e]);
          float ax = fabsf(su) - LAM;
          ax = ax > 0.f ? ax : 0.f;
          (&xv.x)[e] = 5.f * copysignf(ax, su);
        }
        *reinterpret_cast<float4*>(orow + tc) = xv;
      }
      // retire seg k+3 (+this store); seg k+4 stays in flight ACROSS barrier
      asm volatile("s_waitcnt vmcnt(4)" ::: "memory");
      __builtin_amdgcn_s_barrier();
      __builtin_amdgcn_sched_barrier(0);
    }
  } else {
    // ============ edge: one 16-row strip, both 64-col edges ===============
    const int eid = bid - 512;          // 0..255
    const int b0 = eid * 16;
    const int side = tid >> 8;          // waves 0-3 left, 4-7 right
    const int wv = wave & 3;
    const int chunk0 = side ? (4096 - 64) : 0;
    bf16* eb = reinterpret_cast<bf16*>(smem);
    bf16* ys = eb + side * (16 * PYE + 16 * PRE);
    bf16* rs = ys + 16 * PYE;
    float* hs = reinterpret_cast<float*>(smem + 2 * (16 * PYE + 16 * PRE) * 2);
    bf16* h1p = reinterpret_cast<bf16*>(hs + 256);
    bf16* h2p = h1p + 256;

    if (tid < 256) hs[tid] = (tid < 128) ? h[tid] : 0.f;
    __syncthreads();
    if (tid < 256) {   // padded Toeplitz: h1p[p]=h[p-64]; h2p[p]=-h[191-p]
      const int p = tid;
      int i1 = p - 64;
      h1p[p] = ((unsigned)i1 < 128u) ? (bf16)hs[i1] : (bf16)0.f;
      int i2 = 191 - p;
      h2p[p] = ((unsigned)i2 < 128u) ? (bf16)(-hs[i2]) : (bf16)0.f;
    }

    {  // stage y for this side: 352 elems = 88 float4 per row (guarded)
      const int rr = (tid & 255) >> 4;
      const int t = tid & 15;
      const float* yrow = y + (size_t)(b0 + rr) * 4096;
      bf16* dst = ys + rr * PYE;
#pragma unroll
      for (int k = 0; k < 6; ++k) {
        int s4 = t + 16 * k;
        if (s4 < 88) {
          int l = chunk0 - 128 + s4 * 4;
          float4 v;
          if (l >= 0 && l <= 4096 - 4) {
            v = *reinterpret_cast<const float4*>(yrow + l);
          } else {
            v.x = ((unsigned)(l + 0) < 4096u) ? yrow[l + 0] : 0.f;
            v.y = ((unsigned)(l + 1) < 4096u) ? yrow[l + 1] : 0.f;
            v.z = ((unsigned)(l + 2) < 4096u) ? yrow[l + 2] : 0.f;
            v.w = ((unsigned)(l + 3) < 4096u) ? yrow[l + 3] : 0.f;
          }
          bf16x4 bv;
          bv[0] = (bf16)v.x; bv[1] = (bf16)v.y; bv[2] = (bf16)v.z; bv[3] = (bf16)v.w;
          *reinterpret_cast<bf16x4*>(dst + s4 * 4) = bv;
        }
      }
    }
    __syncthreads();

    bf16x8 A1[5], A2[5];
    {
      const int off = 127 + quad * 8 - li;
#pragma unroll
      for (int dd = 0; dd < 5; ++dd) {
        const int o = off + (dd - 2) * 32;   // in [48,215]
        bf16x8 a1, a2;
#pragma unroll
        for (int j = 0; j < 8; ++j) { a1[j] = h1p[o + j]; a2[j] = h2p[o + j]; }
        A1[dd] = a1; A2[dd] = a2;
      }
    }

    // conv1: tiles i0 = -64+16t, t in [0,13); emit -r (truncated to [0,L))
    for (int t = wv; t < 13; t += 4) {
      const int i0 = -64 + 16 * t;
      f32x4 acc;
      {
        bf16x4 yv = *reinterpret_cast<const bf16x4*>(
            ys + li * PYE + (i0 + 128) + quad * 4);
        acc[0] = -(float)yv[0]; acc[1] = -(float)yv[1];
        acc[2] = -(float)yv[2]; acc[3] = -(float)yv[3];
      }
#pragma unroll
      for (int dd = 0; dd < 5; ++dd) {
        bf16x8 b = *reinterpret_cast<const bf16x8*>(
            ys + li * PYE + (i0 + (dd - 2) * 32 + 128) + quad * 8);
        acc = __builtin_amdgcn_mfma_f32_16x16x32_bf16(A1[dd], b, acc, 0, 0, 0);
      }
      bf16x4 rv;
#pragma unroll
      for (int e = 0; e < 4; ++e) {
        int g = chunk0 + i0 + quad * 4 + e;
        float v = ((unsigned)g < 4096u) ? acc[e] : 0.f;
        rv[e] = (bf16)v;
      }
      *reinterpret_cast<bf16x4*>(rs + li * PRE + (i0 + 64) + quad * 4) = rv;
    }
    __syncthreads();

    // conv2 + closed-form epilogue: 4 tiles per side, one per wave
    {
      const int i0 = 16 * wv;
      f32x4 acc = {0.f, 0.f, 0.f, 0.f};
#pragma unroll
      for (int dd = 0; dd < 5; ++dd) {
        bf16x8 b = *reinterpret_cast<const bf16x8*>(
            rs + li * PRE + (i0 + (dd - 2) * 32 + 64) + quad * 8);
        acc = __builtin_amdgcn_mfma_f32_16x16x32_bf16(A2[dd], b, acc, 0, 0, 0);
      }
      float4 xv;
#pragma unroll
      for (int e = 0; e < 4; ++e) {
        float su = s * acc[e];
        float ax = fabsf(su) - LAM;
        ax = ax > 0.f ? ax : 0.f;
        (&xv.x)[e] = 5.f * copysignf(ax, su);
      }
      *reinterpret_cast<float4*>(
          out + (size_t)(b0 + li) * 4096 + chunk0 + i0 + quad * 4) = xv;
    }
  }
}

extern "C" void kernel_launch(void* const* d_in, const int* in_sizes, int n_in,
                              void* d_out, int out_size, void* d_ws,
                              size_t ws_size, hipStream_t stream) {
  const float* y = (const float*)d_in[0];
  const float* h = (const float*)d_in[1];
  const float* s = (const float*)d_in[2];
  float* out = (float*)d_out;
  // 256-B zero block for OOB halo DMA sources (stream-ordered, graph-safe).
  hipMemsetAsync(d_ws, 0, 256, stream);
  // 512 stream blocks (cols [64,4032)) + 256 dual-strip edge blocks (cols
  // [0,64) and [4032,4096)) — disjoint outputs, ONE launch, no prep kernel.
  ista_all<<<dim3(512 + 256), dim3(512), 0, stream>>>(
      y, h, (const float*)d_ws, s, out);
}